// Round 1
// baseline (122.171 us; speedup 1.0000x reference)
//
#include <hip/hip_runtime.h>

#define DIMS 256
#define HK 64
#define NB 4
#define NT 4096
#define BT (NB * NT)

typedef unsigned short u16;
typedef unsigned int u32;

using f32x4  = __attribute__((ext_vector_type(4))) float;
using bf16x8 = __attribute__((ext_vector_type(8))) short;

__device__ __forceinline__ u16 f2bf(float f) {
    u32 u = __float_as_uint(f);
    u = (u + 0x7FFFu + ((u >> 16) & 1u)) >> 16;  // RNE; inputs are finite
    return (u16)u;
}

__device__ __forceinline__ u32 pack2(float a, float b) {
    return (u32)f2bf(a) | ((u32)f2bf(b) << 16);
}

// ---------------- QKV projection (fp32 VALU, W in LDS) ----------------
// grid: 192 blocks x 256 thr. block -> (matrix m = bid%3, row-block bid/3).
// m==0: K, m==1: Q (pre-scaled by 0.125*log2e), m==2: V stored transposed.
__global__ __launch_bounds__(256) void proj_kernel(
    const float* __restrict__ x, const float* __restrict__ wk,
    const float* __restrict__ wq, const float* __restrict__ wv,
    u16* __restrict__ Qb, u16* __restrict__ Kb, u16* __restrict__ Vt)
{
    __shared__ float wl[DIMS * HK];  // 64 KB
    const int bid = blockIdx.x;
    const int m = bid % 3;
    const int rb = bid / 3;
    const float* w = (m == 0) ? wk : (m == 1) ? wq : wv;
    for (int i = threadIdx.x; i < DIMS * HK; i += 256) wl[i] = w[i];
    __syncthreads();

    const int row = rb * 256 + (int)threadIdx.x;
    const f32x4* xr4 = reinterpret_cast<const f32x4*>(x + (size_t)row * DIMS);

    f32x4 acc[16];
    #pragma unroll
    for (int c = 0; c < 16; ++c) acc[c] = f32x4{0.f, 0.f, 0.f, 0.f};

    for (int k4 = 0; k4 < DIMS / 4; ++k4) {
        f32x4 xv = xr4[k4];
        #pragma unroll
        for (int kk = 0; kk < 4; ++kk) {
            const f32x4* wr = reinterpret_cast<const f32x4*>(&wl[(k4 * 4 + kk) * HK]);
            float s = xv[kk];
            #pragma unroll
            for (int c = 0; c < 16; ++c) acc[c] += wr[c] * s;
        }
    }

    if (m == 2) {
        const int bb = row >> 12, t = row & (NT - 1);
        #pragma unroll
        for (int c = 0; c < 16; ++c) {
            #pragma unroll
            for (int kk = 0; kk < 4; ++kk)
                Vt[(size_t)(bb * HK + c * 4 + kk) * NT + t] = f2bf(acc[c][kk]);
        }
    } else {
        const float sc = (m == 1) ? 0.125f * 1.44269504f : 1.0f;
        u16* dst = ((m == 1) ? Qb : Kb) + (size_t)row * HK;
        #pragma unroll
        for (int c = 0; c < 16; ++c) {
            u32 lo_ = pack2(acc[c][0] * sc, acc[c][1] * sc);
            u32 hi_ = pack2(acc[c][2] * sc, acc[c][3] * sc);
            u32* p = reinterpret_cast<u32*>(dst + c * 4);
            p[0] = lo_;
            p[1] = hi_;
        }
    }
}

// ---------------- fused causal attention (flash-style, fixed-max) -------
// grid: 1024 blocks x 64 thr (1 wave). block -> (kv-half h, batch b, pair t).
// Wave handles q-tiles t and 255-t (balanced work), KV tiles of 32 keys,
// p = exp2(s - 28) with Q pre-scaled so s is already in log2 units.
// Writes unnormalized partials Op[h][row][64] and row sums lp[h][row].
__global__ __launch_bounds__(64) void attn_kernel(
    const u16* __restrict__ Qb, const u16* __restrict__ Kb,
    const u16* __restrict__ Vt, float* __restrict__ Op, float* __restrict__ lp)
{
    __shared__ u16 Pl[16 * 40];  // [16 rows][32 keys + 8 pad] bf16
    const int l  = (int)threadIdx.x;
    const int lo = l & 15;
    const int g  = l >> 4;

    const int bid = (int)blockIdx.x;
    const int h  = bid & 1;
    const int pp = bid >> 1;
    const int b  = pp & 3;
    const int tp = pp >> 2;  // 0..127

    #pragma unroll 1
    for (int gi = 0; gi < 2; ++gi) {
        const int qt = gi ? (255 - tp) : tp;
        const int q0 = qt * 16;
        const int nkv = (q0 + 15) / 32 + 1;
        const int it0 = h ? (nkv >> 1) : 0;
        const int it1 = h ? nkv : (nkv >> 1);

        // Q fragments: A-frag row = lo, k = g*8 + j (+32 for second frag)
        const u16* qp = Qb + (size_t)(b * NT + q0 + lo) * HK + g * 8;
        const bf16x8 qf0 = *reinterpret_cast<const bf16x8*>(qp);
        const bf16x8 qf1 = *reinterpret_cast<const bf16x8*>(qp + 32);

        f32x4 o[4];
        float pls[4];
        #pragma unroll
        for (int c = 0; c < 4; ++c) { o[c] = f32x4{0.f, 0.f, 0.f, 0.f}; pls[c] = 0.f; }

        for (int it = it0; it < it1; ++it) {
            const int s0 = it * 32;
            const bool domask = (h == 1) && (it == nkv - 1);

            // K B-frags: col = key (lo), k = head dim
            const u16* kp = Kb + (size_t)(b * NT + s0 + lo) * HK + g * 8;
            bf16x8 k00 = *reinterpret_cast<const bf16x8*>(kp);
            bf16x8 k01 = *reinterpret_cast<const bf16x8*>(kp + 32);
            bf16x8 k10 = *reinterpret_cast<const bf16x8*>(kp + 16 * HK);
            bf16x8 k11 = *reinterpret_cast<const bf16x8*>(kp + 16 * HK + 32);

            // V B-frags from transposed V: col = head dim (lo), k = key
            const u16* vp = Vt + (size_t)(b * HK + lo) * NT + s0 + g * 8;
            bf16x8 v0 = *reinterpret_cast<const bf16x8*>(vp);
            bf16x8 v1 = *reinterpret_cast<const bf16x8*>(vp + 16 * NT);
            bf16x8 v2 = *reinterpret_cast<const bf16x8*>(vp + 32 * NT);
            bf16x8 v3 = *reinterpret_cast<const bf16x8*>(vp + 48 * NT);

            const f32x4 zz = f32x4{0.f, 0.f, 0.f, 0.f};
            f32x4 s_0 = __builtin_amdgcn_mfma_f32_16x16x32_bf16(qf0, k00, zz, 0, 0, 0);
            s_0 = __builtin_amdgcn_mfma_f32_16x16x32_bf16(qf1, k01, s_0, 0, 0, 0);
            f32x4 s_1 = __builtin_amdgcn_mfma_f32_16x16x32_bf16(qf0, k10, zz, 0, 0, 0);
            s_1 = __builtin_amdgcn_mfma_f32_16x16x32_bf16(qf1, k11, s_1, 0, 0, 0);

            #pragma unroll
            for (int ii = 0; ii < 4; ++ii) {
                float sv0 = s_0[ii];
                float sv1 = s_1[ii];
                if (domask) {
                    const int qg = q0 + g * 4 + ii;
                    if (s0 + lo > qg)      sv0 = -1e30f;
                    if (s0 + 16 + lo > qg) sv1 = -1e30f;
                }
                const float p0 = __builtin_amdgcn_exp2f(sv0 - 28.0f);
                const float p1 = __builtin_amdgcn_exp2f(sv1 - 28.0f);
                pls[ii] += p0 + p1;
                Pl[(g * 4 + ii) * 40 + lo]      = f2bf(p0);
                Pl[(g * 4 + ii) * 40 + lo + 16] = f2bf(p1);
            }
            __syncthreads();
            const bf16x8 pf = *reinterpret_cast<const bf16x8*>(&Pl[lo * 40 + g * 8]);
            o[0] = __builtin_amdgcn_mfma_f32_16x16x32_bf16(pf, v0, o[0], 0, 0, 0);
            o[1] = __builtin_amdgcn_mfma_f32_16x16x32_bf16(pf, v1, o[1], 0, 0, 0);
            o[2] = __builtin_amdgcn_mfma_f32_16x16x32_bf16(pf, v2, o[2], 0, 0, 0);
            o[3] = __builtin_amdgcn_mfma_f32_16x16x32_bf16(pf, v3, o[3], 0, 0, 0);
            __syncthreads();
        }

        const size_t rowbase = (size_t)(h * BT + b * NT + q0);
        #pragma unroll
        for (int c = 0; c < 4; ++c) {
            #pragma unroll
            for (int ii = 0; ii < 4; ++ii) {
                Op[(rowbase + g * 4 + ii) * HK + c * 16 + lo] = o[c][ii];
            }
        }
        #pragma unroll
        for (int ii = 0; ii < 4; ++ii) {
            float s = pls[ii];
            s += __shfl_xor(s, 1);
            s += __shfl_xor(s, 2);
            s += __shfl_xor(s, 4);
            s += __shfl_xor(s, 8);
            if (lo == 0) lp[rowbase + g * 4 + ii] = s;
        }
    }
}

// ---------------- merge halves + input copy ----------------
__global__ __launch_bounds__(256) void merge_kernel(
    const float* __restrict__ x, const float* __restrict__ Op,
    const float* __restrict__ lp, float* __restrict__ out)
{
    const int stride = (int)(gridDim.x * blockDim.x);
    const int idx = (int)(blockIdx.x * blockDim.x + threadIdx.x);
    const f32x4* x4 = reinterpret_cast<const f32x4*>(x);
    f32x4* out4 = reinterpret_cast<f32x4*>(out);

    // out[..., 0:256] = inputs  (float4 copy)
    for (int j = idx; j < BT * (DIMS / 4); j += stride) {
        const int row = j >> 6;
        const int c4 = j & 63;
        out4[(size_t)row * 80 + c4] = x4[j];
    }
    // out[..., 256:320] = (O0 + O1) / (l0 + l1)
    for (int j = idx; j < BT * HK; j += stride) {
        const int row = j >> 6;
        const int c = j & 63;
        const float li = lp[row] + lp[BT + row];
        out[(size_t)row * 320 + 256 + c] = (Op[j] + Op[(size_t)BT * HK + j]) / li;
    }
}

extern "C" void kernel_launch(void* const* d_in, const int* in_sizes, int n_in,
                              void* d_out, int out_size, void* d_ws, size_t ws_size,
                              hipStream_t stream) {
    (void)in_sizes; (void)n_in; (void)out_size; (void)ws_size;
    const float* x  = (const float*)d_in[0];
    const float* wk = (const float*)d_in[1];
    const float* wq = (const float*)d_in[2];
    const float* wv = (const float*)d_in[3];
    float* out = (float*)d_out;

    char* ws = (char*)d_ws;
    u16* Qb = (u16*)(ws);                          // 2 MB  [BT][64] bf16
    u16* Kb = (u16*)(ws + ((size_t)2 << 20));      // 2 MB  [BT][64] bf16
    u16* Vt = (u16*)(ws + ((size_t)4 << 20));      // 2 MB  [B][64][T] bf16
    float* Op = (float*)(ws + ((size_t)6 << 20));  // 8 MB  [2][BT][64] f32
    float* lp = (float*)(ws + ((size_t)6 << 20) + (size_t)2 * BT * HK * 4);  // 128 KB

    proj_kernel<<<192, 256, 0, stream>>>(x, wk, wq, wv, Qb, Kb, Vt);
    attn_kernel<<<1024, 64, 0, stream>>>(Qb, Kb, Vt, Op, lp);
    merge_kernel<<<2048, 256, 0, stream>>>(x, Op, lp, out);
}

// Round 2
// 80.089 us; speedup vs baseline: 1.5254x; 1.5254x over previous
//
#include <hip/hip_runtime.h>

#define DIMS 256
#define HK 64
#define NB 4
#define NT 4096
#define BT (NB * NT)

typedef unsigned short u16;
typedef unsigned int u32;

using f32x4  = __attribute__((ext_vector_type(4))) float;
using bf16x8 = __attribute__((ext_vector_type(8))) short;

__device__ __forceinline__ u16 f2bf(float f) {
    u32 u = __float_as_uint(f);
    u = (u + 0x7FFFu + ((u >> 16) & 1u)) >> 16;  // RNE; inputs finite
    return (u16)u;
}
__device__ __forceinline__ u32 pack2(float a, float b) {
    return (u32)f2bf(a) | ((u32)f2bf(b) << 16);
}
__device__ __forceinline__ bf16x8 cvt8(const float* p) {
    f32x4 a = *reinterpret_cast<const f32x4*>(p);
    f32x4 b = *reinterpret_cast<const f32x4*>(p + 4);
    union { u32 w[4]; bf16x8 v; } u;
    u.w[0] = pack2(a[0], a[1]); u.w[1] = pack2(a[2], a[3]);
    u.w[2] = pack2(b[0], b[1]); u.w[3] = pack2(b[2], b[3]);
    return u.v;
}

// ---- prep: Wt[m][col][k] = bf16(W[m][k][col]),  3*64*256 elems ----
__global__ __launch_bounds__(256) void prep_kernel(
    const float* __restrict__ wk, const float* __restrict__ wq,
    const float* __restrict__ wv, u16* __restrict__ Wt)
{
    const int gid = (int)(blockIdx.x * 256 + threadIdx.x);  // 0..12287
    const int e0 = gid * 4;
    const int m = e0 >> 14;
    const int r = e0 & 16383;
    const int col = r >> 8;
    const int k = r & 255;
    const float* w = (m == 0) ? wk : (m == 1) ? wq : wv;
    u32 w0 = pack2(w[(k + 0) * HK + col], w[(k + 1) * HK + col]);
    u32 w1 = pack2(w[(k + 2) * HK + col], w[(k + 3) * HK + col]);
    u32* p = reinterpret_cast<u32*>(Wt + e0);
    p[0] = w0; p[1] = w1;
}

// ---- proj: MFMA bf16 GEMM [BT,256]@[256,64] for Q/K/V ----
// grid 3072 x 64thr: bid -> (m = bid%3, 16-row tile rt = bid/3).
// m==0: K, m==1: Q (pre-scaled 0.125*log2e), m==2: V stored transposed.
__global__ __launch_bounds__(64) void proj_kernel(
    const float* __restrict__ x, const u16* __restrict__ Wt,
    u16* __restrict__ Qb, u16* __restrict__ Kb, u16* __restrict__ Vt)
{
    const int l = (int)threadIdx.x;
    const int lo = l & 15;
    const int g = l >> 4;
    const int bid = (int)blockIdx.x;
    const int m = bid % 3;
    const int q0 = (bid / 3) * 16;

    bf16x8 a[8];
    #pragma unroll
    for (int kf = 0; kf < 8; ++kf)
        a[kf] = cvt8(x + (size_t)(q0 + lo) * DIMS + kf * 32 + g * 8);

    const u16* wb = Wt + m * (HK * DIMS);
    f32x4 acc[4];
    #pragma unroll
    for (int c = 0; c < 4; ++c) acc[c] = f32x4{0.f, 0.f, 0.f, 0.f};

    #pragma unroll
    for (int c = 0; c < 4; ++c) {
        #pragma unroll
        for (int kf = 0; kf < 8; ++kf) {
            bf16x8 bf = *reinterpret_cast<const bf16x8*>(
                wb + (size_t)(16 * c + lo) * DIMS + kf * 32 + g * 8);
            acc[c] = __builtin_amdgcn_mfma_f32_16x16x32_bf16(a[kf], bf, acc[c], 0, 0, 0);
        }
    }

    if (m == 2) {
        #pragma unroll
        for (int c = 0; c < 4; ++c)
            #pragma unroll
            for (int ii = 0; ii < 4; ++ii) {
                const int grow = q0 + 4 * g + ii;
                Vt[(size_t)((grow >> 12) * HK + 16 * c + lo) * NT + (grow & (NT - 1))] =
                    f2bf(acc[c][ii]);
            }
    } else {
        const float sc = (m == 1) ? 0.125f * 1.44269504f : 1.0f;
        u16* dst = (m == 1) ? Qb : Kb;
        #pragma unroll
        for (int c = 0; c < 4; ++c)
            #pragma unroll
            for (int ii = 0; ii < 4; ++ii)
                dst[(size_t)(q0 + 4 * g + ii) * HK + 16 * c + lo] = f2bf(acc[c][ii] * sc);
    }
}

// ---- fused causal attention: 32 q-rows/wave, KV-split S ----
// grid 128*4*S x 64thr. bid -> j desc (long blocks first), b, s.
// p = exp2(s - 28), Q pre-scaled so logits are in log2 units.
__global__ __launch_bounds__(64) void attn_kernel(
    const u16* __restrict__ Qb, const u16* __restrict__ Kb,
    const u16* __restrict__ Vt, float* __restrict__ Op, float* __restrict__ lp,
    const int S)
{
    __shared__ u16 Pl[32 * 40];  // [32 rows][32 keys + 8 pad]
    const int l = (int)threadIdx.x;
    const int lo = l & 15;
    const int g = l >> 4;

    const int bid = (int)blockIdx.x;
    const int per = 4 * S;
    const int j = 127 - bid / per;
    const int r = bid % per;
    const int b = r / S;
    const int s = r % S;

    const int q0 = j * 32;
    const int nkv = j + 1;
    const int it0 = (s * nkv) / S;
    const int it1 = ((s + 1) * nkv) / S;

    bf16x8 qf[2][2];
    #pragma unroll
    for (int rh = 0; rh < 2; ++rh)
        #pragma unroll
        for (int kf = 0; kf < 2; ++kf)
            qf[rh][kf] = *reinterpret_cast<const bf16x8*>(
                Qb + (size_t)(b * NT + q0 + 16 * rh + lo) * HK + kf * 32 + g * 8);

    f32x4 o[2][4];
    float pls[2][4];
    #pragma unroll
    for (int rh = 0; rh < 2; ++rh)
        #pragma unroll
        for (int c = 0; c < 4; ++c) { o[rh][c] = f32x4{0.f, 0.f, 0.f, 0.f}; pls[rh][c] = 0.f; }

    for (int it = it0; it < it1; ++it) {
        const int s0 = it * 32;
        const bool domask = (it == nkv - 1);

        bf16x8 kfr[2][2];
        #pragma unroll
        for (int kh = 0; kh < 2; ++kh)
            #pragma unroll
            for (int kf = 0; kf < 2; ++kf)
                kfr[kh][kf] = *reinterpret_cast<const bf16x8*>(
                    Kb + (size_t)(b * NT + s0 + 16 * kh + lo) * HK + kf * 32 + g * 8);

        bf16x8 vf[4];
        #pragma unroll
        for (int c = 0; c < 4; ++c)
            vf[c] = *reinterpret_cast<const bf16x8*>(
                Vt + (size_t)(b * HK + 16 * c + lo) * NT + s0 + g * 8);

        const f32x4 zz = f32x4{0.f, 0.f, 0.f, 0.f};
        #pragma unroll
        for (int rh = 0; rh < 2; ++rh) {
            #pragma unroll
            for (int kh = 0; kh < 2; ++kh) {
                f32x4 sv = __builtin_amdgcn_mfma_f32_16x16x32_bf16(qf[rh][0], kfr[kh][0], zz, 0, 0, 0);
                sv = __builtin_amdgcn_mfma_f32_16x16x32_bf16(qf[rh][1], kfr[kh][1], sv, 0, 0, 0);
                #pragma unroll
                for (int ii = 0; ii < 4; ++ii) {
                    float v = sv[ii];
                    if (domask) {
                        // key = s0+16kh+lo, row = q0+16rh+4g+ii
                        if (s0 + 16 * kh + lo > q0 + 16 * rh + 4 * g + ii) v = -1e30f;
                    }
                    const float p = __builtin_amdgcn_exp2f(v - 28.0f);
                    pls[rh][ii] += p;
                    Pl[(16 * rh + 4 * g + ii) * 40 + 16 * kh + lo] = f2bf(p);
                }
            }
        }
        __syncthreads();
        bf16x8 pa[2];
        #pragma unroll
        for (int rh = 0; rh < 2; ++rh)
            pa[rh] = *reinterpret_cast<const bf16x8*>(&Pl[(16 * rh + lo) * 40 + g * 8]);
        #pragma unroll
        for (int rh = 0; rh < 2; ++rh)
            #pragma unroll
            for (int c = 0; c < 4; ++c)
                o[rh][c] = __builtin_amdgcn_mfma_f32_16x16x32_bf16(pa[rh], vf[c], o[rh][c], 0, 0, 0);
        __syncthreads();
    }

    const size_t rowbase = (size_t)s * BT + (size_t)b * NT + q0;
    #pragma unroll
    for (int rh = 0; rh < 2; ++rh) {
        #pragma unroll
        for (int c = 0; c < 4; ++c)
            #pragma unroll
            for (int ii = 0; ii < 4; ++ii)
                Op[(rowbase + 16 * rh + 4 * g + ii) * HK + 16 * c + lo] = o[rh][c][ii];
        #pragma unroll
        for (int ii = 0; ii < 4; ++ii) {
            float sum = pls[rh][ii];
            sum += __shfl_xor(sum, 1);
            sum += __shfl_xor(sum, 2);
            sum += __shfl_xor(sum, 4);
            sum += __shfl_xor(sum, 8);
            if (lo == 0) lp[rowbase + 16 * rh + 4 * g + ii] = sum;
        }
    }
}

// ---- merge: out[...,0:256]=x copy; out[...,256:320]=sum(Op)/sum(lp) ----
__global__ __launch_bounds__(256) void merge_kernel(
    const float* __restrict__ x, const float* __restrict__ Op,
    const float* __restrict__ lp, float* __restrict__ out, const int S)
{
    const int stride = (int)(gridDim.x * blockDim.x);
    const int idx = (int)(blockIdx.x * blockDim.x + threadIdx.x);
    const f32x4* x4 = reinterpret_cast<const f32x4*>(x);
    const f32x4* Op4 = reinterpret_cast<const f32x4*>(Op);
    f32x4* out4 = reinterpret_cast<f32x4*>(out);

    for (int jj = idx; jj < BT * (DIMS / 4); jj += stride) {
        const int row = jj >> 6;
        const int c4 = jj & 63;
        out4[(size_t)row * 80 + c4] = x4[jj];
    }
    for (int jj = idx; jj < BT * 16; jj += stride) {
        const int row = jj >> 4;
        const int c4 = jj & 15;
        f32x4 acc = f32x4{0.f, 0.f, 0.f, 0.f};
        float li = 0.f;
        for (int ss = 0; ss < S; ++ss) {
            acc += Op4[((size_t)ss * BT + row) * 16 + c4];
            li += lp[(size_t)ss * BT + row];
        }
        const float inv = 1.0f / li;
        out4[(size_t)row * 80 + 64 + c4] = acc * inv;
    }
}

extern "C" void kernel_launch(void* const* d_in, const int* in_sizes, int n_in,
                              void* d_out, int out_size, void* d_ws, size_t ws_size,
                              hipStream_t stream) {
    (void)in_sizes; (void)n_in; (void)out_size;
    const float* x  = (const float*)d_in[0];
    const float* wk = (const float*)d_in[1];
    const float* wq = (const float*)d_in[2];
    const float* wv = (const float*)d_in[3];
    float* out = (float*)d_out;

    char* ws = (char*)d_ws;
    u16* Qb = (u16*)(ws);                            // 2 MB  [BT][64] bf16
    u16* Kb = (u16*)(ws + ((size_t)2 << 20));        // 2 MB  [BT][64] bf16
    u16* Vt = (u16*)(ws + ((size_t)4 << 20));        // 2 MB  [B][64][T] bf16
    u16* Wt = (u16*)(ws + ((size_t)6 << 20));        // 96 KB [3][64][256] bf16
    float* lp = (float*)(ws + ((size_t)6 << 20) + (256 << 10));   // S*64 KB
    float* Op = (float*)(ws + ((size_t)7 << 20));    // S*4 MB [S][BT][64] f32

    // pick KV-split factor by available workspace
    const size_t per_s = (size_t)BT * HK * 4;  // Op slice (lp fits in reserved gap)
    int S = 8;
    while (S > 1 && ((size_t)7 << 20) + (size_t)S * per_s > ws_size) S >>= 1;

    prep_kernel<<<48, 256, 0, stream>>>(wk, wq, wv, Wt);
    proj_kernel<<<3072, 64, 0, stream>>>(x, Wt, Qb, Kb, Vt);
    attn_kernel<<<128 * 4 * S, 64, 0, stream>>>(Qb, Kb, Vt, Op, lp, S);
    merge_kernel<<<2048, 256, 0, stream>>>(x, Op, lp, out, S);
}

// Round 3
// 75.092 us; speedup vs baseline: 1.6269x; 1.0666x over previous
//
#include <hip/hip_runtime.h>

#define DIMS 256
#define HK 64
#define NB 4
#define NT 4096
#define BT (NB * NT)
#define SMAX 8

typedef unsigned short u16;
typedef unsigned int u32;

using f32x4  = __attribute__((ext_vector_type(4))) float;
using bf16x8 = __attribute__((ext_vector_type(8))) short;
using u32x2  = __attribute__((ext_vector_type(2))) u32;

__device__ __forceinline__ u16 f2bf(float f) {
    u32 u = __float_as_uint(f);
    u = (u + 0x7FFFu + ((u >> 16) & 1u)) >> 16;  // RNE; inputs finite
    return (u16)u;
}
__device__ __forceinline__ u32 pack2(float a, float b) {
    return (u32)f2bf(a) | ((u32)f2bf(b) << 16);
}
__device__ __forceinline__ float bf2f(short h) {
    return __uint_as_float(((u32)(u16)h) << 16);
}
__device__ __forceinline__ bf16x8 ldb8(const u16* p) {
    return *reinterpret_cast<const bf16x8*>(p);
}

// ---- prep: x->out[:,0:256] copy, x->xb bf16, W transpose to Wt ----
__global__ __launch_bounds__(256) void prep_kernel(
    const float* __restrict__ x, const float* __restrict__ wk,
    const float* __restrict__ wq, const float* __restrict__ wv,
    float* __restrict__ out, u32* __restrict__ xb2, u16* __restrict__ Wt)
{
    const int stride = (int)(gridDim.x * blockDim.x);
    const int idx = (int)(blockIdx.x * blockDim.x + threadIdx.x);
    const f32x4* x4 = reinterpret_cast<const f32x4*>(x);
    f32x4* out4 = reinterpret_cast<f32x4*>(out);
    u32x2* xbv = reinterpret_cast<u32x2*>(xb2);

    for (int i = idx; i < BT * 64; i += stride) {
        f32x4 v = x4[i];
        out4[(size_t)(i >> 6) * 80 + (i & 63)] = v;
        u32x2 w;
        w.x = pack2(v[0], v[1]);
        w.y = pack2(v[2], v[3]);
        xbv[i] = w;
    }
    for (int i = idx; i < 12288; i += stride) {
        const int e0 = i * 4;
        const int m = e0 >> 14;
        const int r = e0 & 16383;
        const int col = r >> 8;
        const int k = r & 255;
        const float* w = (m == 0) ? wk : (m == 1) ? wq : wv;
        u32 w0 = pack2(w[(k + 0) * HK + col], w[(k + 1) * HK + col]);
        u32 w1 = pack2(w[(k + 2) * HK + col], w[(k + 3) * HK + col]);
        u32* p = reinterpret_cast<u32*>(Wt + e0);
        p[0] = w0; p[1] = w1;
    }
}

// ---- proj: bf16 MFMA GEMM [BT,256]@[256,64] for Q/K/V ----
__global__ __launch_bounds__(64) void proj_kernel(
    const u16* __restrict__ xb, const u16* __restrict__ Wt,
    u16* __restrict__ Qb, u16* __restrict__ Kb, u16* __restrict__ Vt)
{
    const int l = (int)threadIdx.x;
    const int lo = l & 15;
    const int g = l >> 4;
    const int bid = (int)blockIdx.x;
    const int m = bid % 3;
    const int q0 = (bid / 3) * 16;

    bf16x8 a[8];
    const u16* xrow = xb + (size_t)(q0 + lo) * DIMS + g * 8;
    #pragma unroll
    for (int kf = 0; kf < 8; ++kf) a[kf] = ldb8(xrow + kf * 32);

    const u16* wb = Wt + m * (HK * DIMS);
    f32x4 acc[4];
    #pragma unroll
    for (int c = 0; c < 4; ++c) acc[c] = f32x4{0.f, 0.f, 0.f, 0.f};

    __builtin_amdgcn_s_setprio(1);
    #pragma unroll
    for (int c = 0; c < 4; ++c) {
        #pragma unroll
        for (int kf = 0; kf < 8; ++kf) {
            bf16x8 bf = ldb8(wb + (size_t)(16 * c + lo) * DIMS + kf * 32 + g * 8);
            acc[c] = __builtin_amdgcn_mfma_f32_16x16x32_bf16(a[kf], bf, acc[c], 0, 0, 0);
        }
    }
    __builtin_amdgcn_s_setprio(0);

    if (m == 2) {
        #pragma unroll
        for (int c = 0; c < 4; ++c)
            #pragma unroll
            for (int ii = 0; ii < 4; ++ii) {
                const int grow = q0 + 4 * g + ii;
                Vt[(size_t)((grow >> 12) * HK + 16 * c + lo) * NT + (grow & (NT - 1))] =
                    f2bf(acc[c][ii]);
            }
    } else {
        const float sc = (m == 1) ? 0.125f * 1.44269504f : 1.0f;
        u16* dst = (m == 1) ? Qb : Kb;
        #pragma unroll
        for (int c = 0; c < 4; ++c)
            #pragma unroll
            for (int ii = 0; ii < 4; ++ii)
                dst[(size_t)(q0 + 4 * g + ii) * HK + 16 * c + lo] = f2bf(acc[c][ii] * sc);
    }
}

// ---- attention core helpers (single-wave blocks, no barriers) ----
template<bool MASK>
__device__ __forceinline__ void qk_tile(
    const u16* __restrict__ Kb_b, int s0, int colbase,
    const bf16x8 (&qf)[2][2], float (&pls)[2][4],
    u16 (&Pl)[32 * 72], int lo, int g, int q0)
{
    bf16x8 kk[2][2];
    #pragma unroll
    for (int kh = 0; kh < 2; ++kh)
        #pragma unroll
        for (int kf = 0; kf < 2; ++kf)
            kk[kh][kf] = ldb8(Kb_b + (size_t)(s0 + 16 * kh + lo) * HK + kf * 32 + g * 8);

    const f32x4 zz = f32x4{0.f, 0.f, 0.f, 0.f};
    f32x4 sv[2][2];
    __builtin_amdgcn_s_setprio(1);
    #pragma unroll
    for (int rh = 0; rh < 2; ++rh)
        #pragma unroll
        for (int kh = 0; kh < 2; ++kh) {
            sv[rh][kh] = __builtin_amdgcn_mfma_f32_16x16x32_bf16(qf[rh][0], kk[kh][0], zz, 0, 0, 0);
            sv[rh][kh] = __builtin_amdgcn_mfma_f32_16x16x32_bf16(qf[rh][1], kk[kh][1], sv[rh][kh], 0, 0, 0);
        }
    __builtin_amdgcn_s_setprio(0);

    #pragma unroll
    for (int rh = 0; rh < 2; ++rh)
        #pragma unroll
        for (int kh = 0; kh < 2; ++kh)
            #pragma unroll
            for (int ii = 0; ii < 4; ++ii) {
                float v = sv[rh][kh][ii];
                if (MASK) {
                    if (s0 + 16 * kh + lo > q0 + 16 * rh + 4 * g + ii) v = -1e30f;
                }
                const float p = __builtin_amdgcn_exp2f(v - 28.0f);
                pls[rh][ii] += p;
                Pl[(16 * rh + 4 * g + ii) * 72 + colbase + 16 * kh + lo] = f2bf(p);
            }
}

template<int NKF, bool MASK>
__device__ __forceinline__ void body(
    const u16* __restrict__ Kb_b, const u16* __restrict__ Vb, int s0,
    const bf16x8 (&qf)[2][2], float (&pls)[2][4], f32x4 (&o)[2][4],
    u16 (&Pl)[32 * 72], int lo, int g, int q0)
{
    // hoist V loads: their latency hides under QK + exp2 + transpose
    bf16x8 vf[NKF][4];
    #pragma unroll
    for (int kf = 0; kf < NKF; ++kf)
        #pragma unroll
        for (int c = 0; c < 4; ++c)
            vf[kf][c] = ldb8(Vb + (size_t)(16 * c + lo) * NT + s0 + kf * 32 + g * 8);

    qk_tile<MASK>(Kb_b, s0, 0, qf, pls, Pl, lo, g, q0);
    if (NKF == 2) qk_tile<false>(Kb_b, s0 + 32, 32, qf, pls, Pl, lo, g, q0);

    bf16x8 pa[2][NKF];
    #pragma unroll
    for (int rh = 0; rh < 2; ++rh)
        #pragma unroll
        for (int kf = 0; kf < NKF; ++kf)
            pa[rh][kf] = *reinterpret_cast<const bf16x8*>(&Pl[(16 * rh + lo) * 72 + kf * 32 + g * 8]);

    __builtin_amdgcn_s_setprio(1);
    #pragma unroll
    for (int rh = 0; rh < 2; ++rh)
        #pragma unroll
        for (int c = 0; c < 4; ++c)
            #pragma unroll
            for (int kf = 0; kf < NKF; ++kf)
                o[rh][c] = __builtin_amdgcn_mfma_f32_16x16x32_bf16(pa[rh][kf], vf[kf][c], o[rh][c], 0, 0, 0);
    __builtin_amdgcn_s_setprio(0);
}

// ---- fused causal attention: 32 q-rows/wave, 64 keys/body, KV-split S ----
__global__ __launch_bounds__(64) void attn_kernel(
    const u16* __restrict__ Qb, const u16* __restrict__ Kb,
    const u16* __restrict__ Vt, u16* __restrict__ Opb, float* __restrict__ lp,
    const int S)
{
    __shared__ u16 Pl[32 * 72];  // [32 q-rows][64 keys + 8 pad]
    const int l = (int)threadIdx.x;
    const int lo = l & 15;
    const int g = l >> 4;

    const int bid = (int)blockIdx.x;
    const int per = 4 * S;
    const int j = 127 - bid / per;   // long blocks first
    const int r = bid % per;
    const int b = r / S;
    const int s = r % S;

    const int q0 = j * 32;
    const int nkv = j + 1;                 // 32-key tiles
    const int it0 = (s * nkv) / S;
    const int it1 = ((s + 1) * nkv) / S;

    const u16* Kb_b = Kb + (size_t)b * NT * HK;
    const u16* Vb = Vt + (size_t)b * HK * NT;

    bf16x8 qf[2][2];
    #pragma unroll
    for (int rh = 0; rh < 2; ++rh)
        #pragma unroll
        for (int kf = 0; kf < 2; ++kf)
            qf[rh][kf] = ldb8(Qb + (size_t)(b * NT + q0 + 16 * rh + lo) * HK + kf * 32 + g * 8);

    f32x4 o[2][4];
    float pls[2][4];
    #pragma unroll
    for (int rh = 0; rh < 2; ++rh)
        #pragma unroll
        for (int c = 0; c < 4; ++c) { o[rh][c] = f32x4{0.f, 0.f, 0.f, 0.f}; pls[rh][c] = 0.f; }

    int it = it0;
    const int itE = (s == S - 1) ? it1 - 1 : it1;  // unmasked range end
    for (; it + 1 < itE; it += 2)
        body<2, false>(Kb_b, Vb, it * 32, qf, pls, o, Pl, lo, g, q0);
    if (it < itE)
        body<1, false>(Kb_b, Vb, it * 32, qf, pls, o, Pl, lo, g, q0);
    if (s == S - 1)
        body<1, true>(Kb_b, Vb, (nkv - 1) * 32, qf, pls, o, Pl, lo, g, q0);

    const size_t rowbase = (size_t)s * BT + (size_t)b * NT + q0;
    #pragma unroll
    for (int rh = 0; rh < 2; ++rh) {
        #pragma unroll
        for (int c = 0; c < 4; ++c)
            #pragma unroll
            for (int ii = 0; ii < 4; ++ii)
                Opb[(rowbase + 16 * rh + 4 * g + ii) * HK + 16 * c + lo] = f2bf(o[rh][c][ii]);
        #pragma unroll
        for (int ii = 0; ii < 4; ++ii) {
            float sum = pls[rh][ii];
            sum += __shfl_xor(sum, 1);
            sum += __shfl_xor(sum, 2);
            sum += __shfl_xor(sum, 4);
            sum += __shfl_xor(sum, 8);
            if (lo == 0) lp[rowbase + 16 * rh + 4 * g + ii] = sum;
        }
    }
}

// ---- merge: out[...,256:320] = sum_s(Opb) / sum_s(lp) ----
__global__ __launch_bounds__(256) void merge_kernel(
    const u16* __restrict__ Opb, const float* __restrict__ lp,
    float* __restrict__ out, const int S)
{
    const int idx = (int)(blockIdx.x * 256 + threadIdx.x);  // [0, BT*8)
    const int row = idx >> 3;
    const int c8 = (idx & 7) * 8;

    float li = 0.f;
    for (int s = 0; s < S; ++s) li += lp[(size_t)s * BT + row];

    float acc[8];
    #pragma unroll
    for (int k = 0; k < 8; ++k) acc[k] = 0.f;
    for (int s = 0; s < S; ++s) {
        bf16x8 v = ldb8(Opb + ((size_t)s * BT + row) * HK + c8);
        #pragma unroll
        for (int k = 0; k < 8; ++k) acc[k] += bf2f(v[k]);
    }
    const float inv = 1.0f / li;
    f32x4 r0 = f32x4{acc[0] * inv, acc[1] * inv, acc[2] * inv, acc[3] * inv};
    f32x4 r1 = f32x4{acc[4] * inv, acc[5] * inv, acc[6] * inv, acc[7] * inv};
    f32x4* dst = reinterpret_cast<f32x4*>(out + (size_t)row * 320 + 256 + c8);
    dst[0] = r0;
    dst[1] = r1;
}

extern "C" void kernel_launch(void* const* d_in, const int* in_sizes, int n_in,
                              void* d_out, int out_size, void* d_ws, size_t ws_size,
                              hipStream_t stream) {
    (void)in_sizes; (void)n_in; (void)out_size;
    const float* x  = (const float*)d_in[0];
    const float* wk = (const float*)d_in[1];
    const float* wq = (const float*)d_in[2];
    const float* wv = (const float*)d_in[3];
    float* out = (float*)d_out;

    char* ws = (char*)d_ws;
    u16* Qb  = (u16*)(ws);                           // 2 MB   [BT][64] bf16
    u16* Kb  = (u16*)(ws + ((size_t)2  << 20));      // 2 MB   [BT][64] bf16
    u16* Vt  = (u16*)(ws + ((size_t)4  << 20));      // 2 MB   [B][64][T] bf16
    u32* xb2 = (u32*)(ws + ((size_t)6  << 20));      // 8 MB   [BT][256] bf16
    u16* xb  = (u16*)xb2;
    u16* Wt  = (u16*)(ws + ((size_t)14 << 20));      // 96 KB  [3][64][256] bf16
    float* lp = (float*)(ws + ((size_t)15 << 20));   // ≤512 KB [S][BT] f32
    u16* Opb = (u16*)(ws + ((size_t)16 << 20));      // S*2 MB [S][BT][64] bf16

    int S = SMAX;
    while (S > 1 && ((size_t)16 << 20) + (size_t)S * BT * HK * 2 > ws_size) S >>= 1;

    prep_kernel<<<1024, 256, 0, stream>>>(x, wk, wq, wv, out, xb2, Wt);
    proj_kernel<<<3072, 64, 0, stream>>>(xb, Wt, Qb, Kb, Vt);
    attn_kernel<<<128 * 4 * S, 64, 0, stream>>>(Qb, Kb, Vt, Opb, lp, S);
    merge_kernel<<<512, 256, 0, stream>>>(Opb, lp, out, S);
}